// Round 1
// baseline (122.536 us; speedup 1.0000x reference)
//
#include <hip/hip_runtime.h>

#define DIM 128
#define SLOT_STRIDE 2096                    // 131*16: 130 halo cells + pad; 12-bank rotation/slot
#define PLANE_STRIDE (6 * SLOT_STRIDE)      // 6 y-rows (y0-1 .. y0+4) per z-plane buffer

typedef __attribute__((ext_vector_type(8))) short bf16x8;
typedef __attribute__((ext_vector_type(4))) float f32x4;
typedef __attribute__((ext_vector_type(4))) unsigned int u32x4;

static __device__ __forceinline__ unsigned short f2bf_rne(float f) {
    union { float f; unsigned int i; } c; c.f = f;
    unsigned int u = c.i;
    return (unsigned short)((u + 0x7fffu + ((u >> 16) & 1u)) >> 16);
}
static __device__ __forceinline__ unsigned int fbits(float f) {
    union { float f; unsigned int i; } c; c.f = f; return c.i;
}
static __device__ __forceinline__ unsigned int pack_bf16_rne(float lo, float hi) {
    unsigned int ul = fbits(lo), uh = fbits(hi);
    unsigned int tl = ul + 0x7fffu + ((ul >> 16) & 1u);
    unsigned int th = uh + 0x7fffu + ((uh >> 16) & 1u);
    return __builtin_amdgcn_perm(th, tl, 0x07060302u);
}

struct Frags {
    bf16x8 w1h0, w1h1, w2h;
    f32x4 b1v, b2v;
};

// GEMM1: A = W1^T (bf16 RNE). W1 k-row order: [own | x-1 | x+1 | y-1 | y+1 | z-1 | z+1]
// -> block0 quads {own,x-1,x+1,y-1}, block1 {y+1,z-1,z+1,pad(0)}.
// GEMM2: A2[m=s][k=8q+j] = (j<4) ? W2[4q+j][s] : 0.
static __device__ __forceinline__ void build_frags(
    const float* W1, const float* b1, const float* W2, const float* b2,
    int col, int quad, Frags& F)
{
#pragma unroll
    for (int j = 0; j < 8; ++j) {
        int k0 = quad * 8 + j;
        F.w1h0[j] = (short)f2bf_rne(W1[k0 * 16 + col]);
        int k1 = 32 + quad * 8 + j;
        F.w1h1[j] = (short)f2bf_rne((k1 < 56) ? W1[k1 * 16 + col] : 0.0f);
        float w2 = (j < 4 && col < 8) ? W2[(quad * 4 + j) * 8 + col] : 0.0f;
        F.w2h[j] = (short)f2bf_rne(w2);
    }
#pragma unroll
    for (int r = 0; r < 4; ++r) {
        F.b1v[r] = b1[quad * 4 + r];
        F.b2v[r] = (quad < 2) ? b2[quad * 4 + r] : 0.0f;
    }
}

__global__ __launch_bounds__(64) void setup_kernel(
    const float* __restrict__ W1, const float* __restrict__ b1,
    const float* __restrict__ W2, const float* __restrict__ b2,
    u32x4* __restrict__ ws)
{
    const int lane = threadIdx.x;
    Frags F;
    build_frags(W1, b1, W2, b2, lane & 15, lane >> 4, F);
    union { bf16x8 v; u32x4 u; } c;
    c.v = F.w1h0; ws[0 * 64 + lane] = c.u;
    c.v = F.w1h1; ws[1 * 64 + lane] = c.u;
    c.v = F.w2h;  ws[2 * 64 + lane] = c.u;
    union { f32x4 v; u32x4 u; } b;
    b.v = F.b1v; ws[3 * 64 + lane] = b.u;
    b.v = F.b2v; ws[4 * 64 + lane] = b.u;
}

// z-marching block: (y0..y0+3) x (x all) x (z0..z0+3), 1024 blocks total.
// LDS: 3 rotating plane buffers, each 6 y-rows (y0-1..y0+4) of one z-plane,
// 130 x-cells + x halo. Compute plane z while plane z+2 is prefetched into
// registers (loads issued BEFORE compute, LDS-written after the barrier).
template<bool USE_WS>
__global__ __launch_bounds__(256, 4) void lattice_kernel(
    const float* __restrict__ states,
    const float* __restrict__ W1, const float* __restrict__ b1,
    const float* __restrict__ W2, const float* __restrict__ b2,
    float* __restrict__ out, const u32x4* __restrict__ ws)
{
    __shared__ __align__(16) unsigned char lds[3 * PLANE_STRIDE];   // 37728 B -> 4 blocks/CU

    const int tid  = threadIdx.x;
    const int lane = tid & 63;
    const int w    = __builtin_amdgcn_readfirstlane(tid >> 6);   // wave id = y offset, SGPR
    const int col  = lane & 15;
    const int quad = lane >> 4;

    Frags F;
    if (USE_WS) {
        union { u32x4 u; bf16x8 v; } c;
        c.u = ws[0 * 64 + lane]; F.w1h0 = c.v;
        c.u = ws[1 * 64 + lane]; F.w1h1 = c.v;
        c.u = ws[2 * 64 + lane]; F.w2h  = c.v;
        union { u32x4 u; f32x4 v; } b;
        b.u = ws[3 * 64 + lane]; F.b1v = b.v;
        b.u = ws[4 * 64 + lane]; F.b2v = b.v;
    } else {
        build_frags(W1, b1, W2, b2, col, quad, F);
    }

    // XCD swizzle: blockIdx&7 -> 16-z-plane slab (stays on one XCD's L2).
    // Within slab: inr>>5 = z-sub-slab (4 planes), inr&31 = y0/4 (adjacent
    // blocks share y-halo rows -> L2 hits).
    const int bI   = blockIdx.x;
    const int slab = bI & 7;
    const int inr  = bI >> 3;                    // 0..127
    const int z0   = ((slab << 2) + (inr >> 5)) << 2;
    const int y0   = (inr & 31) << 2;

    // ---- staging helpers: 12 (row,half) tasks per plane, 3 per wave ----
    auto issue_plane = [&](int zp, f32x4* a, f32x4* b) {
#pragma unroll
        for (int i = 0; i < 3; ++i) {
            const int tk   = w * 3 + i;                  // SALU geometry
            const int r    = tk >> 1;
            const int half = tk & 1;
            const int yr   = (y0 - 1 + r) & 127;
            const float* g = states +
                ((size_t)((((unsigned)(zp & 127)) << 14) + (yr << 7) + (half << 6)) << 3);
            a[i] = *(const f32x4*)(g + (lane << 3));
            b[i] = *(const f32x4*)(g + (lane << 3) + 4);
        }
    };
    auto write_plane = [&](int buf, const f32x4* a, const f32x4* b) {
#pragma unroll
        for (int i = 0; i < 3; ++i) {
            const int tk   = w * 3 + i;
            const int r    = tk >> 1;
            const int half = tk & 1;
            u32x4 p;
            p[0] = __builtin_amdgcn_perm(fbits(a[i][1]), fbits(a[i][0]), 0x07060302u);
            p[1] = __builtin_amdgcn_perm(fbits(a[i][3]), fbits(a[i][2]), 0x07060302u);
            p[2] = __builtin_amdgcn_perm(fbits(b[i][1]), fbits(b[i][0]), 0x07060302u);
            p[3] = __builtin_amdgcn_perm(fbits(b[i][3]), fbits(b[i][2]), 0x07060302u);
            unsigned char* base = lds + buf * PLANE_STRIDE + r * SLOT_STRIDE;
            *(u32x4*)(base + ((half * 64 + lane + 1) << 4)) = p;
            // halo: cell 128 <- x=0 (half0 lane0); cell -1 <- x=127 (half1 lane63)
            if (half == 0 && lane == 0)  *(u32x4*)(base + 2064) = p;
            if (half == 1 && lane == 63) *(u32x4*)(base) = p;
        }
    };

    // ---- prologue: planes z0-1, z0, z0+1 -> bufs 0,1,2 (two in flight) ----
    f32x4 gA[3], gB[3], hA[3], hB[3];
    issue_plane(z0 - 1, gA, gB);
    issue_plane(z0,     hA, hB);
    write_plane(0, gA, gB);
    issue_plane(z0 + 1, gA, gB);
    write_plane(1, hA, hB);
    write_plane(2, gA, gB);
    __syncthreads();

    // ---- per-lane LDS offsets (constant across steps; buffer base varies) ----
    const int dxA  = (quad == 1) ? -1 : (quad == 2) ? 1 : 0;
    const int rA   = (quad == 3) ? w : w + 1;            // {own,x-1,x+1}: own row; y-1: row w
    const int rB   = (quad == 0) ? w + 2 : w + 1;        // y+1: row w+2; z+-1/pad: own row
    const int offA = rA * SLOT_STRIDE + ((col + dxA + 1) << 4);
    const int offB = rB * SLOT_STRIDE + ((col + 1) << 4);

#pragma unroll
    for (int s = 0; s < 4; ++s) {
        const int zc = z0 + s;
        if (s < 3) issue_plane(zc + 2, gA, gB);          // prefetch: issue BEFORE compute

        const int bufZm = s % 3, bufZ = (s + 1) % 3, bufZp = (s + 2) % 3;
        const unsigned char* pA = lds + bufZ * PLANE_STRIDE + offA;
        const int bB = (quad == 1) ? bufZm : (quad == 2) ? bufZp : bufZ;
        const unsigned char* pB = lds + bB * PLANE_STRIDE + offB;

        float* pO = out + (size_t)(((zc << 14) + ((y0 + w) << 7) + col) * 8 + quad * 4);

#pragma unroll
        for (int i = 0; i < 8; ++i) {
            bf16x8 s0f = *(const bf16x8*)(pA + (i << 8));
            bf16x8 s1f = *(const bf16x8*)(pB + (i << 8));

            // GEMM1: D1[hidden][cell], bias in C
            f32x4 acc = F.b1v;
            acc = __builtin_amdgcn_mfma_f32_16x16x32_bf16(F.w1h0, s0f, acc, 0, 0, 0);
            acc = __builtin_amdgcn_mfma_f32_16x16x32_bf16(F.w1h1, s1f, acc, 0, 0, 0);

            // tanh
            float h0t, h1t, h2t, h3t;
            {
                float e;
                e = __expf(2.0f * acc[0]); h0t = 1.0f - 2.0f * __builtin_amdgcn_rcpf(e + 1.0f);
                e = __expf(2.0f * acc[1]); h1t = 1.0f - 2.0f * __builtin_amdgcn_rcpf(e + 1.0f);
                e = __expf(2.0f * acc[2]); h2t = 1.0f - 2.0f * __builtin_amdgcn_rcpf(e + 1.0f);
                e = __expf(2.0f * acc[3]); h3t = 1.0f - 2.0f * __builtin_amdgcn_rcpf(e + 1.0f);
            }
            union { bf16x8 v; unsigned int u[4]; } hf;
            hf.u[0] = pack_bf16_rne(h0t, h1t);
            hf.u[1] = pack_bf16_rne(h2t, h3t);
            hf.u[2] = 0u;
            hf.u[3] = 0u;

            // GEMM2: D2[s][cell], bias in C
            f32x4 acc2 = F.b2v;
            acc2 = __builtin_amdgcn_mfma_f32_16x16x32_bf16(F.w2h, hf.v, acc2, 0, 0, 0);

            // store: lanes 0..31 contiguous 512 B; nontemporal (out never re-read)
            if (quad < 2) {
                __builtin_nontemporal_store(acc2, (f32x4*)(pO + (i << 7)));
            }
        }

        __syncthreads();                                 // all reads of buf[s%3] done
        if (s < 3) {
            write_plane(bufZm, gA, gB);                  // vmcnt wait lands here (hidden)
            __syncthreads();                             // new plane visible for next step
        }
    }
}

extern "C" void kernel_launch(void* const* d_in, const int* in_sizes, int n_in,
                              void* d_out, int out_size, void* d_ws, size_t ws_size,
                              hipStream_t stream) {
    const float* states = (const float*)d_in[0];
    const float* W1     = (const float*)d_in[1];
    const float* b1     = (const float*)d_in[2];
    const float* W2     = (const float*)d_in[3];
    const float* b2     = (const float*)d_in[4];
    float* out          = (float*)d_out;

    const bool use_ws = ws_size >= (size_t)(5 * 64 * 16);
    if (use_ws) {
        hipLaunchKernelGGL(setup_kernel, dim3(1), dim3(64), 0, stream,
                           W1, b1, W2, b2, (u32x4*)d_ws);
        hipLaunchKernelGGL((lattice_kernel<true>), dim3(1024), dim3(256), 0, stream,
                           states, W1, b1, W2, b2, out, (const u32x4*)d_ws);
    } else {
        hipLaunchKernelGGL((lattice_kernel<false>), dim3(1024), dim3(256), 0, stream,
                           states, W1, b1, W2, b2, out, (const u32x4*)d_ws);
    }
}

// Round 2
// 122.002 us; speedup vs baseline: 1.0044x; 1.0044x over previous
//
#include <hip/hip_runtime.h>

#define DIM 128
#define SLOT_STRIDE 2096                    // 131*16: 130 halo cells + pad; 12-bank rotation/slot
#define PLANE_STRIDE (6 * SLOT_STRIDE)      // 6 y-rows (y0-1 .. y0+4) per z-plane buffer

typedef __attribute__((ext_vector_type(8))) short bf16x8;
typedef __attribute__((ext_vector_type(4))) float f32x4;
typedef __attribute__((ext_vector_type(4))) unsigned int u32x4;

static __device__ __forceinline__ unsigned short f2bf_rne(float f) {
    union { float f; unsigned int i; } c; c.f = f;
    unsigned int u = c.i;
    return (unsigned short)((u + 0x7fffu + ((u >> 16) & 1u)) >> 16);
}
static __device__ __forceinline__ unsigned int fbits(float f) {
    union { float f; unsigned int i; } c; c.f = f; return c.i;
}
static __device__ __forceinline__ unsigned int pack_bf16_rne(float lo, float hi) {
    unsigned int ul = fbits(lo), uh = fbits(hi);
    unsigned int tl = ul + 0x7fffu + ((ul >> 16) & 1u);
    unsigned int th = uh + 0x7fffu + ((uh >> 16) & 1u);
    return __builtin_amdgcn_perm(th, tl, 0x07060302u);
}

struct Frags {
    bf16x8 w1h0, w1h1, w2h;
    f32x4 b1v, b2v;
};

// GEMM1: A = W1^T (bf16 RNE). W1 k-row order: [own | x-1 | x+1 | y-1 | y+1 | z-1 | z+1]
// -> block0 quads {own,x-1,x+1,y-1}, block1 {y+1,z-1,z+1,pad(0)}.
// GEMM2: A2[m=s][k=8q+j] = (j<4) ? W2[4q+j][s] : 0.
static __device__ __forceinline__ void build_frags(
    const float* W1, const float* b1, const float* W2, const float* b2,
    int col, int quad, Frags& F)
{
#pragma unroll
    for (int j = 0; j < 8; ++j) {
        int k0 = quad * 8 + j;
        F.w1h0[j] = (short)f2bf_rne(W1[k0 * 16 + col]);
        int k1 = 32 + quad * 8 + j;
        F.w1h1[j] = (short)f2bf_rne((k1 < 56) ? W1[k1 * 16 + col] : 0.0f);
        float w2 = (j < 4 && col < 8) ? W2[(quad * 4 + j) * 8 + col] : 0.0f;
        F.w2h[j] = (short)f2bf_rne(w2);
    }
#pragma unroll
    for (int r = 0; r < 4; ++r) {
        F.b1v[r] = b1[quad * 4 + r];
        F.b2v[r] = (quad < 2) ? b2[quad * 4 + r] : 0.0f;
    }
}

__global__ __launch_bounds__(64) void setup_kernel(
    const float* __restrict__ W1, const float* __restrict__ b1,
    const float* __restrict__ W2, const float* __restrict__ b2,
    u32x4* __restrict__ ws)
{
    const int lane = threadIdx.x;
    Frags F;
    build_frags(W1, b1, W2, b2, lane & 15, lane >> 4, F);
    union { bf16x8 v; u32x4 u; } c;
    c.v = F.w1h0; ws[0 * 64 + lane] = c.u;
    c.v = F.w1h1; ws[1 * 64 + lane] = c.u;
    c.v = F.w2h;  ws[2 * 64 + lane] = c.u;
    union { f32x4 v; u32x4 u; } b;
    b.v = F.b1v; ws[3 * 64 + lane] = b.u;
    b.v = F.b2v; ws[4 * 64 + lane] = b.u;
}

// z-marching block: (y0..y0+3) x (x all) x (z0..z0+3), 1024 blocks total.
// LDS: FOUR rotating plane buffers (z-1, z, z+1, write-target), 6 y-rows each.
// Per step: issue loads for z+3 -> LDS-write plane z+2 (loads issued one FULL
// step ago; vmcnt wait covered by last step's compute) -> compute z -> ONE
// barrier. Buffer written at step s (buf (s+3)%4) held z-2, dead since the
// previous barrier, so no pre-write barrier is needed (vs 2 barriers/step
// with 3 buffers).
template<bool USE_WS>
__global__ __launch_bounds__(256, 3) void lattice_kernel(
    const float* __restrict__ states,
    const float* __restrict__ W1, const float* __restrict__ b1,
    const float* __restrict__ W2, const float* __restrict__ b2,
    float* __restrict__ out, const u32x4* __restrict__ ws)
{
    __shared__ __align__(16) unsigned char lds[4 * PLANE_STRIDE];   // 50304 B -> 3 blocks/CU

    const int tid  = threadIdx.x;
    const int lane = tid & 63;
    const int w    = __builtin_amdgcn_readfirstlane(tid >> 6);   // wave id = y offset, SGPR
    const int col  = lane & 15;
    const int quad = lane >> 4;

    Frags F;
    if (USE_WS) {
        union { u32x4 u; bf16x8 v; } c;
        c.u = ws[0 * 64 + lane]; F.w1h0 = c.v;
        c.u = ws[1 * 64 + lane]; F.w1h1 = c.v;
        c.u = ws[2 * 64 + lane]; F.w2h  = c.v;
        union { u32x4 u; f32x4 v; } b;
        b.u = ws[3 * 64 + lane]; F.b1v = b.v;
        b.u = ws[4 * 64 + lane]; F.b2v = b.v;
    } else {
        build_frags(W1, b1, W2, b2, col, quad, F);
    }

    // XCD swizzle: blockIdx&7 -> 16-z-plane slab (stays on one XCD's L2).
    // Within slab: inr>>5 = z-sub-slab (4 planes), inr&31 = y0/4 (adjacent
    // blocks share y-halo rows -> L2 hits).
    const int bI   = blockIdx.x;
    const int slab = bI & 7;
    const int inr  = bI >> 3;                    // 0..127
    const int z0   = ((slab << 2) + (inr >> 5)) << 2;
    const int y0   = (inr & 31) << 2;

    // ---- staging helpers: 12 (row,half) tasks per plane, 3 per wave ----
    auto issue_plane = [&](int zp, f32x4* a, f32x4* b) {
#pragma unroll
        for (int i = 0; i < 3; ++i) {
            const int tk   = w * 3 + i;                  // SALU geometry
            const int r    = tk >> 1;
            const int half = tk & 1;
            const int yr   = (y0 - 1 + r) & 127;
            const float* g = states +
                ((size_t)((((unsigned)(zp & 127)) << 14) + (yr << 7) + (half << 6)) << 3);
            a[i] = *(const f32x4*)(g + (lane << 3));
            b[i] = *(const f32x4*)(g + (lane << 3) + 4);
        }
    };
    auto write_plane = [&](int buf, const f32x4* a, const f32x4* b) {
#pragma unroll
        for (int i = 0; i < 3; ++i) {
            const int tk   = w * 3 + i;
            const int r    = tk >> 1;
            const int half = tk & 1;
            u32x4 p;
            p[0] = __builtin_amdgcn_perm(fbits(a[i][1]), fbits(a[i][0]), 0x07060302u);
            p[1] = __builtin_amdgcn_perm(fbits(a[i][3]), fbits(a[i][2]), 0x07060302u);
            p[2] = __builtin_amdgcn_perm(fbits(b[i][1]), fbits(b[i][0]), 0x07060302u);
            p[3] = __builtin_amdgcn_perm(fbits(b[i][3]), fbits(b[i][2]), 0x07060302u);
            unsigned char* base = lds + buf * PLANE_STRIDE + r * SLOT_STRIDE;
            *(u32x4*)(base + ((half * 64 + lane + 1) << 4)) = p;
            // halo: cell 128 <- x=0 (half0 lane0); cell -1 <- x=127 (half1 lane63)
            if (half == 0 && lane == 0)  *(u32x4*)(base + 2064) = p;
            if (half == 1 && lane == 63) *(u32x4*)(base) = p;
        }
    };

    // ---- per-lane LDS offsets (constant across steps; buffer base varies) ----
    const int dxA  = (quad == 1) ? -1 : (quad == 2) ? 1 : 0;
    const int rA   = (quad == 3) ? w : w + 1;            // {own,x-1,x+1}: own row; y-1: row w
    const int rB   = (quad == 0) ? w + 2 : w + 1;        // y+1: row w+2; z+-1/pad: own row
    const int offA = rA * SLOT_STRIDE + ((col + dxA + 1) << 4);
    const int offB = rB * SLOT_STRIDE + ((col + 1) << 4);

    auto compute_step = [&](int zc, int bufZm, int bufZ, int bufZp) {
        const unsigned char* pA = lds + bufZ * PLANE_STRIDE + offA;
        const int bB = (quad == 1) ? bufZm : (quad == 2) ? bufZp : bufZ;
        const unsigned char* pB = lds + bB * PLANE_STRIDE + offB;
        float* pO = out + (size_t)(((zc << 14) + ((y0 + w) << 7) + col) * 8 + quad * 4);

#pragma unroll
        for (int i = 0; i < 8; ++i) {
            bf16x8 s0f = *(const bf16x8*)(pA + (i << 8));
            bf16x8 s1f = *(const bf16x8*)(pB + (i << 8));

            // GEMM1: D1[hidden][cell], bias in C
            f32x4 acc = F.b1v;
            acc = __builtin_amdgcn_mfma_f32_16x16x32_bf16(F.w1h0, s0f, acc, 0, 0, 0);
            acc = __builtin_amdgcn_mfma_f32_16x16x32_bf16(F.w1h1, s1f, acc, 0, 0, 0);

            // tanh
            float h0t, h1t, h2t, h3t;
            {
                float e;
                e = __expf(2.0f * acc[0]); h0t = 1.0f - 2.0f * __builtin_amdgcn_rcpf(e + 1.0f);
                e = __expf(2.0f * acc[1]); h1t = 1.0f - 2.0f * __builtin_amdgcn_rcpf(e + 1.0f);
                e = __expf(2.0f * acc[2]); h2t = 1.0f - 2.0f * __builtin_amdgcn_rcpf(e + 1.0f);
                e = __expf(2.0f * acc[3]); h3t = 1.0f - 2.0f * __builtin_amdgcn_rcpf(e + 1.0f);
            }
            union { bf16x8 v; unsigned int u[4]; } hf;
            hf.u[0] = pack_bf16_rne(h0t, h1t);
            hf.u[1] = pack_bf16_rne(h2t, h3t);
            hf.u[2] = 0u;
            hf.u[3] = 0u;

            // GEMM2: D2[s][cell], bias in C
            f32x4 acc2 = F.b2v;
            acc2 = __builtin_amdgcn_mfma_f32_16x16x32_bf16(F.w2h, hf.v, acc2, 0, 0, 0);

            // store: lanes 0..31 contiguous 512 B; nontemporal (out never re-read)
            if (quad < 2) {
                __builtin_nontemporal_store(acc2, (f32x4*)(pO + (i << 7)));
            }
        }
    };

    // ---- prologue: planes z0-1..z0+2; two reg sets ping-pong ----
    f32x4 Aa[3], Ab[3], Ba[3], Bb[3];
    issue_plane(z0 - 1, Aa, Ab);
    issue_plane(z0,     Ba, Bb);
    write_plane(0, Aa, Ab);                  // z0-1
    issue_plane(z0 + 1, Aa, Ab);
    write_plane(1, Ba, Bb);                  // z0
    issue_plane(z0 + 2, Ba, Bb);
    write_plane(2, Aa, Ab);                  // z0+1
    __syncthreads();

    // ---- steady: issue(z+3) -> write(z+2, full-step-old loads) -> compute(z) -> barrier
    // step 0
    issue_plane(z0 + 3, Aa, Ab);
    write_plane(3, Ba, Bb);                  // z0+2
    compute_step(z0 + 0, 0, 1, 2);
    __syncthreads();
    // step 1
    issue_plane(z0 + 4, Ba, Bb);
    write_plane(0, Aa, Ab);                  // z0+3 (buf0's z0-1 dead since step0 barrier)
    compute_step(z0 + 1, 1, 2, 3);
    __syncthreads();
    // step 2
    write_plane(1, Ba, Bb);                  // z0+4
    compute_step(z0 + 2, 2, 3, 0);
    __syncthreads();
    // step 3
    compute_step(z0 + 3, 3, 0, 1);
}

extern "C" void kernel_launch(void* const* d_in, const int* in_sizes, int n_in,
                              void* d_out, int out_size, void* d_ws, size_t ws_size,
                              hipStream_t stream) {
    const float* states = (const float*)d_in[0];
    const float* W1     = (const float*)d_in[1];
    const float* b1     = (const float*)d_in[2];
    const float* W2     = (const float*)d_in[3];
    const float* b2     = (const float*)d_in[4];
    float* out          = (float*)d_out;

    const bool use_ws = ws_size >= (size_t)(5 * 64 * 16);
    if (use_ws) {
        hipLaunchKernelGGL(setup_kernel, dim3(1), dim3(64), 0, stream,
                           W1, b1, W2, b2, (u32x4*)d_ws);
        hipLaunchKernelGGL((lattice_kernel<true>), dim3(1024), dim3(256), 0, stream,
                           states, W1, b1, W2, b2, out, (const u32x4*)d_ws);
    } else {
        hipLaunchKernelGGL((lattice_kernel<false>), dim3(1024), dim3(256), 0, stream,
                           states, W1, b1, W2, b2, out, (const u32x4*)d_ws);
    }
}